// Round 1
// baseline (661.319 us; speedup 1.0000x reference)
//
#include <hip/hip_runtime.h>
#include <hip/hip_bf16.h>
#include <math.h>

// Problem constants (fixed by setup_inputs): B=4096, D=512, V=50000.
#define B_ROWS 4096
#define DIMS   512
#define V_ROWS 50000
#define V_PAD  50048            // 391 * 128
#define NTILES 391              // V_PAD / 128
#define MTILES 32               // B_ROWS / 128
#define BK     64
#define EPSF   1e-8f

typedef __bf16 bf16x8 __attribute__((ext_vector_type(8)));
typedef float  f32x4  __attribute__((ext_vector_type(4)));

__device__ __forceinline__ unsigned short f32_to_bf16_bits(float x) {
  union { __bf16 h; unsigned short u; } cv;
  cv.h = (__bf16)x;          // RN conversion
  return cv.u;
}

// async global->LDS, 16B per lane. LDS dest is wave-uniform base + lane*16.
__device__ __forceinline__ void lds_load16(const ushort* g, ushort* l) {
  __builtin_amdgcn_global_load_lds(
      (__attribute__((address_space(1))) void*)g,
      (__attribute__((address_space(3))) void*)l, 16, 0, 0);
}

// merge two sorted (v0>=v1) top-2 pairs, no index tie-break (deterministic order)
__device__ __forceinline__ void merge2(float& v0, int& i0, float& v1, int& i1,
                                       float ov0, int oi0, float ov1, int oi1) {
  bool bt = ov0 > v0;
  float lv = bt ? v0 : ov0; int li = bt ? i0 : oi0;   // loser of top compare
  float hv = bt ? ov1 : v1; int hi = bt ? oi1 : i1;   // runner-up of winner
  if (bt) { v0 = ov0; i0 = oi0; }
  bool b2 = hv > lv;
  v1 = b2 ? hv : lv; i1 = b2 ? hi : li;
}

// value-strict, index tie-break (matches jax top_k first-occurrence semantics)
__device__ __forceinline__ bool better(float v, int i, float w, int j) {
  return (v > w) || (v == w && i < j);
}

__device__ __forceinline__ void merge2t(float& v0, int& i0, float& v1, int& i1,
                                        float ov0, int oi0, float ov1, int oi1) {
  bool bt = better(ov0, oi0, v0, i0);
  float lv = bt ? v0 : ov0; int li = bt ? i0 : oi0;
  float hv = bt ? ov1 : v1; int hi = bt ? oi1 : i1;
  if (bt) { v0 = ov0; i0 = oi0; }
  bool b2 = better(hv, hi, lv, li);
  v1 = b2 ? hv : lv; i1 = b2 ? hi : li;
}

// ---------------------------------------------------------------------------
// K1/K2: row-normalize fp32 -> bf16. One 256-thread block per row (D=512).
// Pad rows (>= nvalid) are zero-filled so the GEMM can read them safely.
// ---------------------------------------------------------------------------
__global__ __launch_bounds__(256)
void normalize_rows_kernel(const float* __restrict__ src, ushort* __restrict__ dst,
                           int nvalid) {
  const int row = blockIdx.x;
  const int t = threadIdx.x;
  if (row >= nvalid) {
    ((unsigned int*)dst)[(size_t)row * 256 + t] = 0u;  // 256 uints = 512 bf16
    return;
  }
  __shared__ float wsum[4];
  float2 v = ((const float2*)src)[(size_t)row * 256 + t];
  float ss = v.x * v.x + v.y * v.y;
  #pragma unroll
  for (int d = 1; d < 64; d <<= 1) ss += __shfl_xor(ss, d);
  if ((t & 63) == 0) wsum[t >> 6] = ss;
  __syncthreads();
  float tot = wsum[0] + wsum[1] + wsum[2] + wsum[3];
  float scale = 1.0f / fmaxf(sqrtf(tot), EPSF);
  ushort2 o;
  o.x = f32_to_bf16_bits(v.x * scale);
  o.y = f32_to_bf16_bits(v.y * scale);
  ((ushort2*)dst)[(size_t)row * 256 + t] = o;
}

// ---------------------------------------------------------------------------
// K3: bf16 MFMA GEMM (m97 structure) + per-block top-2 epilogue.
// A = inn [4096][512] bf16, Bm = vnn [50048][512] bf16 (N x K, i.e. B^T form).
// Each 256-thread block computes a 128x128 tile of sims and reduces it to
// top-2 (value, col) per row; candidates written to cands[ntile][row_global].
// ---------------------------------------------------------------------------
__global__ __launch_bounds__(256, 2)
void gemm_top2_kernel(const ushort* __restrict__ A, const ushort* __restrict__ Bm,
                      float4* __restrict__ cands) {
  __shared__ __align__(16) ushort As[128 * BK];
  __shared__ __align__(16) ushort Bs[128 * BK];
  __shared__ float4 wcand[128][2];

  const int bid = blockIdx.x;
  const int mt = bid & 31;        // fast index: 32 consecutive blocks share B-tile
  const int nt = bid >> 5;        // 0..390
  const int m0 = mt * 128, n0 = nt * 128;

  const int tid = threadIdx.x;
  const int w = tid >> 6, l = tid & 63;
  const int wr = w >> 1, wc = w & 1;     // 2x2 wave grid, 64x64 per wave
  const int lq = l >> 4, lr = l & 15;

  f32x4 acc[4][4] = {};

  for (int k0 = 0; k0 < DIMS; k0 += BK) {
    // stage A,B tiles: 1024 16B-chunks each; wave w covers chunks [it*256+w*64, +64)
    #pragma unroll
    for (int it = 0; it < 4; ++it) {
      const int chunk = it * 256 + w * 64 + l;   // 0..1023
      const int row = chunk >> 3, cc = chunk & 7;
      lds_load16(A + (size_t)(m0 + row) * DIMS + k0 + cc * 8,
                 &As[(size_t)(it * 256 + w * 64) * 8]);
      lds_load16(Bm + (size_t)(n0 + row) * DIMS + k0 + cc * 8,
                 &Bs[(size_t)(it * 256 + w * 64) * 8]);
    }
    __syncthreads();
    #pragma unroll
    for (int ks = 0; ks < BK; ks += 32) {
      bf16x8 af[4], bfr[4];
      #pragma unroll
      for (int tt = 0; tt < 4; ++tt) {
        af[tt]  = *(const bf16x8*)&As[(wr * 64 + tt * 16 + lr) * BK + ks + lq * 8];
        bfr[tt] = *(const bf16x8*)&Bs[(wc * 64 + tt * 16 + lr) * BK + ks + lq * 8];
      }
      #pragma unroll
      for (int tr = 0; tr < 4; ++tr)
        #pragma unroll
        for (int tc = 0; tc < 4; ++tc)
          acc[tr][tc] = __builtin_amdgcn_mfma_f32_16x16x32_bf16(
              af[tr], bfr[tc], acc[tr][tc], 0, 0, 0);
    }
    __syncthreads();
  }

  // mask padded columns (only last N tile)
  const int colbase = n0 + wc * 64 + lr;
  #pragma unroll
  for (int tc = 0; tc < 4; ++tc) {
    if (colbase + tc * 16 >= V_ROWS) {
      #pragma unroll
      for (int tr = 0; tr < 4; ++tr)
        #pragma unroll
        for (int r = 0; r < 4; ++r)
          acc[tr][tc][r] = -1e30f;
    }
  }

  // per-row top-2 over this block's 128 cols.
  // C/D layout: row = (lane>>4)*4 + reg, col = lane&15 (per 16x16 tile).
  #pragma unroll
  for (int tr = 0; tr < 4; ++tr) {
    #pragma unroll
    for (int reg = 0; reg < 4; ++reg) {
      float v0 = -INFINITY, v1 = -INFINITY;
      int i0 = 0, i1 = 0;
      #pragma unroll
      for (int tc = 0; tc < 4; ++tc) {
        float v = acc[tr][tc][reg];
        int col = colbase + tc * 16;
        bool b0 = v > v0;
        bool b1 = v > v1;
        float sv1 = b0 ? v0 : (b1 ? v : v1);
        int   si1 = b0 ? i0 : (b1 ? col : i1);
        v0 = b0 ? v : v0;
        i0 = b0 ? col : i0;
        v1 = sv1; i1 = si1;
      }
      // butterfly across the 16 lanes sharing this row (low 4 lane bits)
      #pragma unroll
      for (int d = 1; d < 16; d <<= 1) {
        float ov0 = __shfl_xor(v0, d); int oi0 = __shfl_xor(i0, d);
        float ov1 = __shfl_xor(v1, d); int oi1 = __shfl_xor(i1, d);
        merge2(v0, i0, v1, i1, ov0, oi0, ov1, oi1);
      }
      if (lr == 0) {
        int rloc = wr * 64 + tr * 16 + lq * 4 + reg;
        wcand[rloc][wc] = make_float4(v0, __int_as_float(i0), v1, __int_as_float(i1));
      }
    }
  }
  __syncthreads();
  if (tid < 128) {
    float4 a = wcand[tid][0], b4 = wcand[tid][1];
    float v0 = a.x; int i0 = __float_as_int(a.y);
    float v1 = a.z; int i1 = __float_as_int(a.w);
    merge2(v0, i0, v1, i1, b4.x, __float_as_int(b4.y), b4.z, __float_as_int(b4.w));
    cands[(size_t)nt * B_ROWS + m0 + tid] =
        make_float4(v0, __int_as_float(i0), v1, __int_as_float(i1));
  }
}

// ---------------------------------------------------------------------------
// K4: zero the scalar output (d_out is poisoned before every call)
// ---------------------------------------------------------------------------
__global__ void zero_out_kernel(float* out) {
  if (threadIdx.x == 0 && blockIdx.x == 0) out[0] = 0.0f;
}

// ---------------------------------------------------------------------------
// K5: per-row final. Merge 391 tile candidates -> global top-2 indices, then
// recompute d_pos / d_neg exactly in fp32 from the original inputs
// (mirrors reference _cos_dist), and atomicAdd the loss contribution.
// ---------------------------------------------------------------------------
__global__ __launch_bounds__(256)
void finalize_kernel(const float* __restrict__ input, const float* __restrict__ target,
                     const float* __restrict__ veclist, const float4* __restrict__ cands,
                     float* __restrict__ out) {
  const int b = blockIdx.x;
  const int t = threadIdx.x;
  __shared__ float4 wpair[4];
  __shared__ int sidx[2];
  __shared__ float red[4][7];
  __shared__ int reda[4];

  // phase A: global top-2 across tiles
  float v0 = -INFINITY, v1 = -INFINITY;
  int i0 = 0x7FFFFFFF, i1 = 0x7FFFFFFF;
  for (int nt = t; nt < NTILES; nt += 256) {
    float4 c = cands[(size_t)nt * B_ROWS + b];
    float cv0 = c.x; int ci0 = __float_as_int(c.y);
    float cv1 = c.z; int ci1 = __float_as_int(c.w);
    if (better(cv0, ci0, v0, i0)) { v1 = v0; i1 = i0; v0 = cv0; i0 = ci0; }
    else if (better(cv0, ci0, v1, i1)) { v1 = cv0; i1 = ci0; }
    if (better(cv1, ci1, v0, i0)) { v1 = v0; i1 = i0; v0 = cv1; i0 = ci1; }
    else if (better(cv1, ci1, v1, i1)) { v1 = cv1; i1 = ci1; }
  }
  #pragma unroll
  for (int d = 1; d < 64; d <<= 1) {
    float ov0 = __shfl_xor(v0, d); int oi0 = __shfl_xor(i0, d);
    float ov1 = __shfl_xor(v1, d); int oi1 = __shfl_xor(i1, d);
    merge2t(v0, i0, v1, i1, ov0, oi0, ov1, oi1);
  }
  if ((t & 63) == 0) wpair[t >> 6] = make_float4(v0, __int_as_float(i0),
                                                 v1, __int_as_float(i1));
  __syncthreads();
  if (t == 0) {
    float4 p = wpair[0];
    float m0v = p.x; int m0i = __float_as_int(p.y);
    float m1v = p.z; int m1i = __float_as_int(p.w);
    for (int wd = 1; wd < 4; ++wd) {
      float4 q = wpair[wd];
      merge2t(m0v, m0i, m1v, m1i, q.x, __float_as_int(q.y),
              q.z, __float_as_int(q.w));
    }
    sidx[0] = m0i; sidx[1] = m1i;
  }
  __syncthreads();
  const int idx0 = sidx[0], idx1 = sidx[1];

  // phase B: exact fp32 dot products / norms (256 threads x float2 = 512 elems)
  const float2* xin = (const float2*)(input  + (size_t)b * DIMS);
  const float2* xtg = (const float2*)(target + (size_t)b * DIMS);
  const float2* xv0 = (const float2*)(veclist + (size_t)idx0 * DIMS);
  const float2* xv1 = (const float2*)(veclist + (size_t)idx1 * DIMS);
  float2 xi = xin[t], tg = xtg[t], a0 = xv0[t], a1 = xv1[t];
  float s[7];
  s[0] = xi.x * xi.x + xi.y * xi.y;   // ||input||^2
  s[1] = tg.x * tg.x + tg.y * tg.y;   // ||target||^2
  s[2] = xi.x * tg.x + xi.y * tg.y;   // input . target
  s[3] = a0.x * a0.x + a0.y * a0.y;   // ||vec0||^2
  s[4] = xi.x * a0.x + xi.y * a0.y;   // input . vec0
  s[5] = a1.x * a1.x + a1.y * a1.y;   // ||vec1||^2
  s[6] = xi.x * a1.x + xi.y * a1.y;   // input . vec1
  bool eq = (a0.x == tg.x) && (a0.y == tg.y);
  int weq = __all(eq);
  #pragma unroll
  for (int k = 0; k < 7; ++k)
    #pragma unroll
    for (int d = 1; d < 64; d <<= 1) s[k] += __shfl_xor(s[k], d);
  if ((t & 63) == 0) {
    #pragma unroll
    for (int k = 0; k < 7; ++k) red[t >> 6][k] = s[k];
    reda[t >> 6] = weq;
  }
  __syncthreads();
  if (t == 0) {
    float r[7];
    #pragma unroll
    for (int k = 0; k < 7; ++k)
      r[k] = red[0][k] + red[1][k] + red[2][k] + red[3][k];
    bool eq0 = reda[0] && reda[1] && reda[2] && reda[3];
    float na  = fmaxf(sqrtf(r[0]), EPSF);
    float ntg = fmaxf(sqrtf(r[1]), EPSF);
    float simp = r[2] / (na * ntg);
    float d_pos = sqrtf(fmaxf(2.0f * (1.0f - simp), 1e-12f));
    float nn = eq0 ? fmaxf(sqrtf(r[5]), EPSF) : fmaxf(sqrtf(r[3]), EPSF);
    float dn = eq0 ? r[6] : r[4];
    float simn = dn / (na * nn);
    float d_neg = sqrtf(fmaxf(2.0f * (1.0f - simn), 1e-12f));
    float margin = 0.5f + d_pos - d_neg;          // GAMMA + d_pos - d_neg
    float contrib = 2.0f * fmaxf(margin, 0.0f) * (1.0f / (float)B_ROWS);  // RANK=2
    atomicAdd(out, contrib);
  }
}

// ---------------------------------------------------------------------------
// Workspace layout (bytes):
//   vnn  bf16 [50048][512]  @ 0          : 51,249,152
//   inn  bf16 [4096][512]   @ 51,249,152 :  4,194,304
//   cands float4 [391][4096] @ 55,443,456: 25,624,576   (total ~81.1 MB)
// ---------------------------------------------------------------------------
extern "C" void kernel_launch(void* const* d_in, const int* in_sizes, int n_in,
                              void* d_out, int out_size, void* d_ws, size_t ws_size,
                              hipStream_t stream) {
  const float* input   = (const float*)d_in[0];
  const float* target  = (const float*)d_in[1];
  const float* veclist = (const float*)d_in[2];
  float* out = (float*)d_out;
  char* ws = (char*)d_ws;
  ushort* vnn = (ushort*)ws;
  ushort* inn = (ushort*)(ws + 51249152);
  float4* cands = (float4*)(ws + 51249152 + 4194304);

  normalize_rows_kernel<<<V_PAD, 256, 0, stream>>>(veclist, vnn, V_ROWS);
  normalize_rows_kernel<<<B_ROWS, 256, 0, stream>>>(input, inn, B_ROWS);
  zero_out_kernel<<<1, 64, 0, stream>>>(out);
  gemm_top2_kernel<<<MTILES * NTILES, 256, 0, stream>>>(inn, vnn, cands);
  finalize_kernel<<<B_ROWS, 256, 0, stream>>>(input, target, veclist, cands, out);
}

// Round 2
// 568.903 us; speedup vs baseline: 1.1624x; 1.1624x over previous
//
#include <hip/hip_runtime.h>
#include <hip/hip_bf16.h>
#include <math.h>

// Problem constants (fixed by setup_inputs): B=4096, D=512, V=50000.
#define B_ROWS 4096
#define DIMS   512
#define V_ROWS 50000
#define V_PAD  50048            // 391 * 128
#define NTILES 391              // V_PAD / 128
#define MTILES 32               // B_ROWS / 128
#define BK     64
#define EPSF   1e-8f

typedef __bf16 bf16x8 __attribute__((ext_vector_type(8)));
typedef float  f32x4  __attribute__((ext_vector_type(4)));
typedef unsigned short ushort8 __attribute__((ext_vector_type(8)));

__device__ __forceinline__ unsigned short f32_to_bf16_bits(float x) {
  union { __bf16 h; unsigned short u; } cv;
  cv.h = (__bf16)x;          // RN conversion
  return cv.u;
}

// async global->LDS, 16B per lane. LDS dest is wave-uniform base + lane*16.
__device__ __forceinline__ void lds_load16(const ushort* g, ushort* l) {
  __builtin_amdgcn_global_load_lds(
      (__attribute__((address_space(1))) void*)g,
      (__attribute__((address_space(3))) void*)l, 16, 0, 0);
}

// merge two sorted (v0>=v1) top-2 pairs, no index tie-break
__device__ __forceinline__ void merge2(float& v0, int& i0, float& v1, int& i1,
                                       float ov0, int oi0, float ov1, int oi1) {
  bool bt = ov0 > v0;
  float lv = bt ? v0 : ov0; int li = bt ? i0 : oi0;
  float hv = bt ? ov1 : v1; int hi = bt ? oi1 : i1;
  if (bt) { v0 = ov0; i0 = oi0; }
  bool b2 = hv > lv;
  v1 = b2 ? hv : lv; i1 = b2 ? hi : li;
}

// value-strict, index tie-break (matches jax top_k first-occurrence semantics)
__device__ __forceinline__ bool better(float v, int i, float w, int j) {
  return (v > w) || (v == w && i < j);
}

__device__ __forceinline__ void merge2t(float& v0, int& i0, float& v1, int& i1,
                                        float ov0, int oi0, float ov1, int oi1) {
  bool bt = better(ov0, oi0, v0, i0);
  float lv = bt ? v0 : ov0; int li = bt ? i0 : oi0;
  float hv = bt ? ov1 : v1; int hi = bt ? oi1 : i1;
  if (bt) { v0 = ov0; i0 = oi0; }
  bool b2 = better(hv, hi, lv, li);
  v1 = b2 ? hv : lv; i1 = b2 ? hi : li;
}

// ---------------------------------------------------------------------------
// K1/K2: row-normalize fp32 -> bf16. One WAVE per row (D=512: 64 lanes x 8
// elems), grid-stride. Pad rows (>= nvalid) zero-filled for the GEMM.
// ---------------------------------------------------------------------------
__global__ __launch_bounds__(256)
void normalize_rows_kernel(const float* __restrict__ src, ushort* __restrict__ dst,
                           int nvalid, int ntotal) {
  const int l = threadIdx.x & 63;
  const int gw = (blockIdx.x * 256 + threadIdx.x) >> 6;
  const int nw = (gridDim.x * 256) >> 6;
  for (int row = gw; row < ntotal; row += nw) {
    if (row >= nvalid) {
      ((uint4*)dst)[(size_t)row * 64 + l] = make_uint4(0u, 0u, 0u, 0u);
      continue;
    }
    float4 v0 = ((const float4*)src)[(size_t)row * 128 + l * 2];
    float4 v1 = ((const float4*)src)[(size_t)row * 128 + l * 2 + 1];
    float ss = v0.x * v0.x + v0.y * v0.y + v0.z * v0.z + v0.w * v0.w
             + v1.x * v1.x + v1.y * v1.y + v1.z * v1.z + v1.w * v1.w;
    #pragma unroll
    for (int d = 1; d < 64; d <<= 1) ss += __shfl_xor(ss, d);
    float scale = 1.0f / fmaxf(sqrtf(ss), EPSF);
    ushort8 o;
    o[0] = f32_to_bf16_bits(v0.x * scale); o[1] = f32_to_bf16_bits(v0.y * scale);
    o[2] = f32_to_bf16_bits(v0.z * scale); o[3] = f32_to_bf16_bits(v0.w * scale);
    o[4] = f32_to_bf16_bits(v1.x * scale); o[5] = f32_to_bf16_bits(v1.y * scale);
    o[6] = f32_to_bf16_bits(v1.z * scale); o[7] = f32_to_bf16_bits(v1.w * scale);
    *(ushort8*)&dst[(size_t)row * DIMS + l * 8] = o;
  }
}

// ---------------------------------------------------------------------------
// K3: bf16 MFMA GEMM (m97 structure) + XOR-swizzled LDS + top-2 epilogue.
// LDS layout: tile row r, chunk slot c (16B chunks) holds global chunk
// c ^ (r&7). Staging permutes the GLOBAL chunk index (DMA lane->LDS mapping
// is fixed at base+lane*16); fragment reads apply the same XOR. This spreads
// the 16 same-quad lanes of each ds_read_b128 across all 8 chunk slots
// (2 lanes/bank-group = free, m136) instead of 16-way on one group.
// ---------------------------------------------------------------------------
__global__ __launch_bounds__(256, 2)
void gemm_top2_kernel(const ushort* __restrict__ A, const ushort* __restrict__ Bm,
                      float4* __restrict__ cands) {
  __shared__ __align__(16) ushort As[128 * BK];
  __shared__ __align__(16) ushort Bs[128 * BK];
  __shared__ float4 wcand[128][2];

  const int bid = blockIdx.x;
  const int mt = bid & 31;        // 32 consecutive blocks share the B-tile
  const int nt = bid >> 5;        // 0..390
  const int m0 = mt * 128, n0 = nt * 128;

  const int tid = threadIdx.x;
  const int w = tid >> 6, l = tid & 63;
  const int wr = w >> 1, wc = w & 1;     // 2x2 wave grid, 64x64 per wave
  const int lq = l >> 4, lr = l & 15;

  f32x4 acc[4][4] = {};

  for (int k0 = 0; k0 < DIMS; k0 += BK) {
    #pragma unroll
    for (int it = 0; it < 4; ++it) {
      const int chunk = it * 256 + w * 64 + l;   // 0..1023
      const int row = chunk >> 3, c = chunk & 7;
      const int gc = c ^ (row & 7);              // swizzled global chunk
      lds_load16(A + (size_t)(m0 + row) * DIMS + k0 + gc * 8,
                 &As[(size_t)(it * 256 + w * 64) * 8]);
      lds_load16(Bm + (size_t)(n0 + row) * DIMS + k0 + gc * 8,
                 &Bs[(size_t)(it * 256 + w * 64) * 8]);
    }
    __syncthreads();
    #pragma unroll
    for (int ks = 0; ks < BK; ks += 32) {
      const int c0 = ks >> 3;                    // 0 or 4
      const int sw = ((c0 + lq) ^ (lr & 7)) * 8; // swizzled slot (ushort units)
      bf16x8 af[4], bfr[4];
      #pragma unroll
      for (int tt = 0; tt < 4; ++tt) {
        af[tt]  = *(const bf16x8*)&As[(wr * 64 + tt * 16 + lr) * BK + sw];
        bfr[tt] = *(const bf16x8*)&Bs[(wc * 64 + tt * 16 + lr) * BK + sw];
      }
      #pragma unroll
      for (int tr = 0; tr < 4; ++tr)
        #pragma unroll
        for (int tc = 0; tc < 4; ++tc)
          acc[tr][tc] = __builtin_amdgcn_mfma_f32_16x16x32_bf16(
              af[tr], bfr[tc], acc[tr][tc], 0, 0, 0);
    }
    __syncthreads();
  }

  // mask padded columns (only last N tile)
  const int colbase = n0 + wc * 64 + lr;
  #pragma unroll
  for (int tc = 0; tc < 4; ++tc) {
    if (colbase + tc * 16 >= V_ROWS) {
      #pragma unroll
      for (int tr = 0; tr < 4; ++tr)
        #pragma unroll
        for (int r = 0; r < 4; ++r)
          acc[tr][tc][r] = -1e30f;
    }
  }

  // per-row top-2 over this block's 128 cols.
  // C/D layout: row = (lane>>4)*4 + reg, col = lane&15 (per 16x16 tile).
  #pragma unroll
  for (int tr = 0; tr < 4; ++tr) {
    #pragma unroll
    for (int reg = 0; reg < 4; ++reg) {
      float v0 = -INFINITY, v1 = -INFINITY;
      int i0 = 0, i1 = 0;
      #pragma unroll
      for (int tc = 0; tc < 4; ++tc) {
        float v = acc[tr][tc][reg];
        int col = colbase + tc * 16;
        bool b0 = v > v0;
        bool b1 = v > v1;
        float sv1 = b0 ? v0 : (b1 ? v : v1);
        int   si1 = b0 ? i0 : (b1 ? col : i1);
        v0 = b0 ? v : v0;
        i0 = b0 ? col : i0;
        v1 = sv1; i1 = si1;
      }
      #pragma unroll
      for (int d = 1; d < 16; d <<= 1) {
        float ov0 = __shfl_xor(v0, d); int oi0 = __shfl_xor(i0, d);
        float ov1 = __shfl_xor(v1, d); int oi1 = __shfl_xor(i1, d);
        merge2(v0, i0, v1, i1, ov0, oi0, ov1, oi1);
      }
      if (lr == 0) {
        int rloc = wr * 64 + tr * 16 + lq * 4 + reg;
        wcand[rloc][wc] = make_float4(v0, __int_as_float(i0), v1, __int_as_float(i1));
      }
    }
  }
  __syncthreads();
  if (tid < 128) {
    float4 a = wcand[tid][0], b4 = wcand[tid][1];
    float v0 = a.x; int i0 = __float_as_int(a.y);
    float v1 = a.z; int i1 = __float_as_int(a.w);
    merge2(v0, i0, v1, i1, b4.x, __float_as_int(b4.y), b4.z, __float_as_int(b4.w));
    cands[(size_t)nt * B_ROWS + m0 + tid] =
        make_float4(v0, __int_as_float(i0), v1, __int_as_float(i1));
  }
}

// ---------------------------------------------------------------------------
// K4: zero the scalar output (d_out is poisoned before every call)
// ---------------------------------------------------------------------------
__global__ void zero_out_kernel(float* out) {
  if (threadIdx.x == 0 && blockIdx.x == 0) out[0] = 0.0f;
}

// ---------------------------------------------------------------------------
// K5: per-row final. Merge 391 tile candidates -> global top-2 indices, then
// recompute d_pos / d_neg exactly in fp32 from the original inputs.
// ---------------------------------------------------------------------------
__global__ __launch_bounds__(256)
void finalize_kernel(const float* __restrict__ input, const float* __restrict__ target,
                     const float* __restrict__ veclist, const float4* __restrict__ cands,
                     float* __restrict__ out) {
  const int b = blockIdx.x;
  const int t = threadIdx.x;
  __shared__ float4 wpair[4];
  __shared__ int sidx[2];
  __shared__ float red[4][7];
  __shared__ int reda[4];

  // phase A: global top-2 across tiles
  float v0 = -INFINITY, v1 = -INFINITY;
  int i0 = 0x7FFFFFFF, i1 = 0x7FFFFFFF;
  for (int nt = t; nt < NTILES; nt += 256) {
    float4 c = cands[(size_t)nt * B_ROWS + b];
    float cv0 = c.x; int ci0 = __float_as_int(c.y);
    float cv1 = c.z; int ci1 = __float_as_int(c.w);
    if (better(cv0, ci0, v0, i0)) { v1 = v0; i1 = i0; v0 = cv0; i0 = ci0; }
    else if (better(cv0, ci0, v1, i1)) { v1 = cv0; i1 = ci0; }
    if (better(cv1, ci1, v0, i0)) { v1 = v0; i1 = i0; v0 = cv1; i0 = ci1; }
    else if (better(cv1, ci1, v1, i1)) { v1 = cv1; i1 = ci1; }
  }
  #pragma unroll
  for (int d = 1; d < 64; d <<= 1) {
    float ov0 = __shfl_xor(v0, d); int oi0 = __shfl_xor(i0, d);
    float ov1 = __shfl_xor(v1, d); int oi1 = __shfl_xor(i1, d);
    merge2t(v0, i0, v1, i1, ov0, oi0, ov1, oi1);
  }
  if ((t & 63) == 0) wpair[t >> 6] = make_float4(v0, __int_as_float(i0),
                                                 v1, __int_as_float(i1));
  __syncthreads();
  if (t == 0) {
    float4 p = wpair[0];
    float m0v = p.x; int m0i = __float_as_int(p.y);
    float m1v = p.z; int m1i = __float_as_int(p.w);
    for (int wd = 1; wd < 4; ++wd) {
      float4 q = wpair[wd];
      merge2t(m0v, m0i, m1v, m1i, q.x, __float_as_int(q.y),
              q.z, __float_as_int(q.w));
    }
    sidx[0] = m0i; sidx[1] = m1i;
  }
  __syncthreads();
  const int idx0 = sidx[0], idx1 = sidx[1];

  // phase B: exact fp32 dot products / norms
  const float2* xin = (const float2*)(input  + (size_t)b * DIMS);
  const float2* xtg = (const float2*)(target + (size_t)b * DIMS);
  const float2* xv0 = (const float2*)(veclist + (size_t)idx0 * DIMS);
  const float2* xv1 = (const float2*)(veclist + (size_t)idx1 * DIMS);
  float2 xi = xin[t], tg = xtg[t], a0 = xv0[t], a1 = xv1[t];
  float s[7];
  s[0] = xi.x * xi.x + xi.y * xi.y;
  s[1] = tg.x * tg.x + tg.y * tg.y;
  s[2] = xi.x * tg.x + xi.y * tg.y;
  s[3] = a0.x * a0.x + a0.y * a0.y;
  s[4] = xi.x * a0.x + xi.y * a0.y;
  s[5] = a1.x * a1.x + a1.y * a1.y;
  s[6] = xi.x * a1.x + xi.y * a1.y;
  bool eq = (a0.x == tg.x) && (a0.y == tg.y);
  int weq = __all(eq);
  #pragma unroll
  for (int k = 0; k < 7; ++k)
    #pragma unroll
    for (int d = 1; d < 64; d <<= 1) s[k] += __shfl_xor(s[k], d);
  if ((t & 63) == 0) {
    #pragma unroll
    for (int k = 0; k < 7; ++k) red[t >> 6][k] = s[k];
    reda[t >> 6] = weq;
  }
  __syncthreads();
  if (t == 0) {
    float r[7];
    #pragma unroll
    for (int k = 0; k < 7; ++k)
      r[k] = red[0][k] + red[1][k] + red[2][k] + red[3][k];
    bool eq0 = reda[0] && reda[1] && reda[2] && reda[3];
    float na  = fmaxf(sqrtf(r[0]), EPSF);
    float ntg = fmaxf(sqrtf(r[1]), EPSF);
    float simp = r[2] / (na * ntg);
    float d_pos = sqrtf(fmaxf(2.0f * (1.0f - simp), 1e-12f));
    float nn = eq0 ? fmaxf(sqrtf(r[5]), EPSF) : fmaxf(sqrtf(r[3]), EPSF);
    float dn = eq0 ? r[6] : r[4];
    float simn = dn / (na * nn);
    float d_neg = sqrtf(fmaxf(2.0f * (1.0f - simn), 1e-12f));
    float margin = 0.5f + d_pos - d_neg;          // GAMMA + d_pos - d_neg
    float contrib = 2.0f * fmaxf(margin, 0.0f) * (1.0f / (float)B_ROWS);  // RANK=2
    atomicAdd(out, contrib);
  }
}

// ---------------------------------------------------------------------------
// Workspace layout (bytes):
//   vnn  bf16 [50048][512]  @ 0          : 51,249,152
//   inn  bf16 [4096][512]   @ 51,249,152 :  4,194,304
//   cands float4 [391][4096] @ 55,443,456: 25,624,576   (total ~81.1 MB)
// ---------------------------------------------------------------------------
extern "C" void kernel_launch(void* const* d_in, const int* in_sizes, int n_in,
                              void* d_out, int out_size, void* d_ws, size_t ws_size,
                              hipStream_t stream) {
  const float* input   = (const float*)d_in[0];
  const float* target  = (const float*)d_in[1];
  const float* veclist = (const float*)d_in[2];
  float* out = (float*)d_out;
  char* ws = (char*)d_ws;
  ushort* vnn = (ushort*)ws;
  ushort* inn = (ushort*)(ws + 51249152);
  float4* cands = (float4*)(ws + 51249152 + 4194304);

  normalize_rows_kernel<<<2048, 256, 0, stream>>>(veclist, vnn, V_ROWS, V_PAD);
  normalize_rows_kernel<<<512, 256, 0, stream>>>(input, inn, B_ROWS, B_ROWS);
  zero_out_kernel<<<1, 64, 0, stream>>>(out);
  gemm_top2_kernel<<<MTILES * NTILES, 256, 0, stream>>>(inn, vnn, cands);
  finalize_kernel<<<B_ROWS, 256, 0, stream>>>(input, target, veclist, cands, out);
}

// Round 3
// 487.703 us; speedup vs baseline: 1.3560x; 1.1665x over previous
//
#include <hip/hip_runtime.h>
#include <hip/hip_bf16.h>
#include <hip/hip_fp8.h>
#include <math.h>

// Problem constants (fixed by setup_inputs): B=4096, D=512, V=50000.
#define B_ROWS 4096
#define DIMS   512
#define V_ROWS 50000
#define V_PAD  50048            // 391 * 128
#define NTILES 391              // V_PAD / 128
#define NT_PAD 392              // cands row stride (float4 units)
#define MTILES 32               // B_ROWS / 128
#define BKB    128              // K-bytes (fp8 elems) staged per iteration
#define EPSF   1e-8f
#define QSCALE 64.0f            // row pre-scale before fp8 quant (dodges e4m3 subnormals)

typedef float f32x4 __attribute__((ext_vector_type(4)));

// fp8 e4m3 (OCP) pack of 4 floats -> u32, bytes little-endian in k order
__device__ __forceinline__ unsigned int pk4_fp8(float a, float b, float c, float d) {
#if __has_builtin(__builtin_amdgcn_cvt_pk_fp8_f32)
  int w = __builtin_amdgcn_cvt_pk_fp8_f32(a, b, 0, false);   // bytes 0,1
  w = __builtin_amdgcn_cvt_pk_fp8_f32(c, d, w, true);        // bytes 2,3
  return (unsigned int)w;
#else
  __hip_fp8_e4m3 qa(a), qb(b), qc(c), qd(d);
  return (unsigned int)qa.__x | ((unsigned int)qb.__x << 8) |
         ((unsigned int)qc.__x << 16) | ((unsigned int)qd.__x << 24);
#endif
}

// async global->LDS, 16B per lane. LDS dest is wave-uniform base + lane*16.
__device__ __forceinline__ void lds_load16(const void* g, void* l) {
  __builtin_amdgcn_global_load_lds(
      (const __attribute__((address_space(1))) void*)g,
      (__attribute__((address_space(3))) void*)l, 16, 0, 0);
}

// merge two sorted (v0>=v1) top-2 pairs, no index tie-break
__device__ __forceinline__ void merge2(float& v0, int& i0, float& v1, int& i1,
                                       float ov0, int oi0, float ov1, int oi1) {
  bool bt = ov0 > v0;
  float lv = bt ? v0 : ov0; int li = bt ? i0 : oi0;
  float hv = bt ? ov1 : v1; int hi = bt ? oi1 : i1;
  if (bt) { v0 = ov0; i0 = oi0; }
  bool b2 = hv > lv;
  v1 = b2 ? hv : lv; i1 = b2 ? hi : li;
}

// value-strict, index tie-break (matches jax top_k first-occurrence semantics)
__device__ __forceinline__ bool better(float v, int i, float w, int j) {
  return (v > w) || (v == w && i < j);
}

__device__ __forceinline__ void merge2t(float& v0, int& i0, float& v1, int& i1,
                                        float ov0, int oi0, float ov1, int oi1) {
  bool bt = better(ov0, oi0, v0, i0);
  float lv = bt ? v0 : ov0; int li = bt ? i0 : oi0;
  float hv = bt ? ov1 : v1; int hi = bt ? oi1 : i1;
  if (bt) { v0 = ov0; i0 = oi0; }
  bool b2 = better(hv, hi, lv, li);
  v1 = b2 ? hv : lv; i1 = b2 ? hi : li;
}

// ---------------------------------------------------------------------------
// K1/K2: row-normalize fp32 -> fp8 e4m3 (scaled by QSCALE). One WAVE per row
// (64 lanes x 8 elems), grid-stride. Pad rows zero-filled. Also zeroes the
// scalar output (d_out poisoned before every call) from block 0 when out!=0.
// ---------------------------------------------------------------------------
__global__ __launch_bounds__(256)
void normalize_rows_kernel(const float* __restrict__ src, unsigned char* __restrict__ dst,
                           int nvalid, int ntotal, float* out_zero) {
  if (out_zero != nullptr && blockIdx.x == 0 && threadIdx.x == 0) *out_zero = 0.0f;
  const int l = threadIdx.x & 63;
  const int gw = (blockIdx.x * 256 + threadIdx.x) >> 6;
  const int nw = (gridDim.x * 256) >> 6;
  for (int row = gw; row < ntotal; row += nw) {
    if (row >= nvalid) {
      *(uint2*)&dst[(size_t)row * DIMS + l * 8] = make_uint2(0u, 0u);
      continue;
    }
    float4 v0 = ((const float4*)src)[(size_t)row * 128 + l * 2];
    float4 v1 = ((const float4*)src)[(size_t)row * 128 + l * 2 + 1];
    float ss = v0.x * v0.x + v0.y * v0.y + v0.z * v0.z + v0.w * v0.w
             + v1.x * v1.x + v1.y * v1.y + v1.z * v1.z + v1.w * v1.w;
    #pragma unroll
    for (int d = 1; d < 64; d <<= 1) ss += __shfl_xor(ss, d);
    float s = QSCALE / fmaxf(sqrtf(ss), EPSF);
    uint2 o;
    o.x = pk4_fp8(v0.x * s, v0.y * s, v0.z * s, v0.w * s);
    o.y = pk4_fp8(v1.x * s, v1.y * s, v1.z * s, v1.w * s);
    *(uint2*)&dst[(size_t)row * DIMS + l * 8] = o;
  }
}

// ---------------------------------------------------------------------------
// K3: fp8 MFMA GEMM (16x16x32_fp8_fp8), BK=128 bytes/stage (4 K-iterations),
// XOR-8 swizzled LDS, top-2 epilogue. LDS row = 128 B = 8 x 16B chunks; slot s
// of row r holds global chunk s^(r&7). Fragment ds_read_b64 banks work out to
// 4 lane-dwords/bank (balanced = conflict-free). Sims are scaled by QSCALE^2
// (monotone -> argmax/top-2 invariant; exact values recomputed in finalize).
// ---------------------------------------------------------------------------
__global__ __launch_bounds__(256, 4)
void gemm_top2_kernel(const unsigned char* __restrict__ A8,
                      const unsigned char* __restrict__ B8,
                      float4* __restrict__ cands) {
  __shared__ __align__(16) unsigned char As[128 * BKB];   // 16 KB
  __shared__ __align__(16) unsigned char Bs[128 * BKB];   // 16 KB
  __shared__ float4 wcand[128][2];                        //  4 KB

  const int bid = blockIdx.x;
  const int mt = bid & 31;        // 32 consecutive blocks share the B-tile
  const int nt = bid >> 5;        // 0..390
  const int m0 = mt * 128, n0 = nt * 128;

  const int tid = threadIdx.x;
  const int w = tid >> 6, l = tid & 63;
  const int wr = w >> 1, wc = w & 1;     // 2x2 wave grid, 64x64 per wave
  const int lq = l >> 4, lr = l & 15;

  f32x4 acc[4][4] = {};

  for (int k0 = 0; k0 < DIMS; k0 += BKB) {
    // stage A,B fp8 tiles: 1024 16B-chunks each (128 rows x 8 chunks)
    #pragma unroll
    for (int it = 0; it < 4; ++it) {
      const int chunk = it * 256 + w * 64 + l;   // 0..1023
      const int row = chunk >> 3, c = chunk & 7;
      const int gc = c ^ (row & 7);              // swizzled global chunk
      lds_load16(A8 + (size_t)(m0 + row) * DIMS + k0 + gc * 16,
                 &As[(it * 256 + w * 64) * 16]);
      lds_load16(B8 + (size_t)(n0 + row) * DIMS + k0 + gc * 16,
                 &Bs[(it * 256 + w * 64) * 16]);
    }
    __syncthreads();
    #pragma unroll
    for (int ks = 0; ks < BKB; ks += 32) {
      const int g = (ks >> 4) + (lq >> 1);       // global chunk 0..7
      const int off = (lq & 1) * 8;              // 8-byte half within chunk
      const int slot = (g ^ (lr & 7)) * 16 + off;
      long af[4], bf_[4];
      #pragma unroll
      for (int tt = 0; tt < 4; ++tt) {
        af[tt]  = *(const long*)&As[(wr * 64 + tt * 16 + lr) * BKB + slot];
        bf_[tt] = *(const long*)&Bs[(wc * 64 + tt * 16 + lr) * BKB + slot];
      }
      #pragma unroll
      for (int tr = 0; tr < 4; ++tr)
        #pragma unroll
        for (int tc = 0; tc < 4; ++tc)
          acc[tr][tc] = __builtin_amdgcn_mfma_f32_16x16x32_fp8_fp8(
              af[tr], bf_[tc], acc[tr][tc], 0, 0, 0);
    }
    __syncthreads();
  }

  // mask padded columns (only last N tile)
  const int colbase = n0 + wc * 64 + lr;
  #pragma unroll
  for (int tc = 0; tc < 4; ++tc) {
    if (colbase + tc * 16 >= V_ROWS) {
      #pragma unroll
      for (int tr = 0; tr < 4; ++tr)
        #pragma unroll
        for (int r = 0; r < 4; ++r)
          acc[tr][tc][r] = -1e30f;
    }
  }

  // per-row top-2 over this block's 128 cols.
  // C/D layout: row = (lane>>4)*4 + reg, col = lane&15 (per 16x16 tile).
  #pragma unroll
  for (int tr = 0; tr < 4; ++tr) {
    #pragma unroll
    for (int reg = 0; reg < 4; ++reg) {
      float v0 = -INFINITY, v1 = -INFINITY;
      int i0 = 0, i1 = 0;
      #pragma unroll
      for (int tc = 0; tc < 4; ++tc) {
        float v = acc[tr][tc][reg];
        int col = colbase + tc * 16;
        bool b0 = v > v0;
        bool b1 = v > v1;
        float sv1 = b0 ? v0 : (b1 ? v : v1);
        int   si1 = b0 ? i0 : (b1 ? col : i1);
        v0 = b0 ? v : v0;
        i0 = b0 ? col : i0;
        v1 = sv1; i1 = si1;
      }
      #pragma unroll
      for (int d = 1; d < 16; d <<= 1) {
        float ov0 = __shfl_xor(v0, d); int oi0 = __shfl_xor(i0, d);
        float ov1 = __shfl_xor(v1, d); int oi1 = __shfl_xor(i1, d);
        merge2(v0, i0, v1, i1, ov0, oi0, ov1, oi1);
      }
      if (lr == 0) {
        int rloc = wr * 64 + tr * 16 + lq * 4 + reg;
        wcand[rloc][wc] = make_float4(v0, __int_as_float(i0), v1, __int_as_float(i1));
      }
    }
  }
  __syncthreads();
  if (tid < 128) {
    float4 a = wcand[tid][0], b4 = wcand[tid][1];
    float v0 = a.x; int i0 = __float_as_int(a.y);
    float v1 = a.z; int i1 = __float_as_int(a.w);
    merge2(v0, i0, v1, i1, b4.x, __float_as_int(b4.y), b4.z, __float_as_int(b4.w));
    // transposed layout: [row][tile] so finalize reads are coalesced
    cands[(size_t)(m0 + tid) * NT_PAD + nt] =
        make_float4(v0, __int_as_float(i0), v1, __int_as_float(i1));
  }
}

// ---------------------------------------------------------------------------
// K5: per-row final. Merge 391 tile candidates -> global top-2 indices, then
// recompute d_pos / d_neg exactly in fp32 from the original inputs.
// ---------------------------------------------------------------------------
__global__ __launch_bounds__(256)
void finalize_kernel(const float* __restrict__ input, const float* __restrict__ target,
                     const float* __restrict__ veclist, const float4* __restrict__ cands,
                     float* __restrict__ out) {
  const int b = blockIdx.x;
  const int t = threadIdx.x;
  __shared__ float4 wpair[4];
  __shared__ int sidx[2];
  __shared__ float red[4][7];
  __shared__ int reda[4];

  // phase A: global top-2 across tiles (coalesced: cands[b][nt])
  float v0 = -INFINITY, v1 = -INFINITY;
  int i0 = 0x7FFFFFFF, i1 = 0x7FFFFFFF;
  for (int nt = t; nt < NTILES; nt += 256) {
    float4 c = cands[(size_t)b * NT_PAD + nt];
    float cv0 = c.x; int ci0 = __float_as_int(c.y);
    float cv1 = c.z; int ci1 = __float_as_int(c.w);
    if (better(cv0, ci0, v0, i0)) { v1 = v0; i1 = i0; v0 = cv0; i0 = ci0; }
    else if (better(cv0, ci0, v1, i1)) { v1 = cv0; i1 = ci0; }
    if (better(cv1, ci1, v0, i0)) { v1 = v0; i1 = i0; v0 = cv1; i0 = ci1; }
    else if (better(cv1, ci1, v1, i1)) { v1 = cv1; i1 = ci1; }
  }
  #pragma unroll
  for (int d = 1; d < 64; d <<= 1) {
    float ov0 = __shfl_xor(v0, d); int oi0 = __shfl_xor(i0, d);
    float ov1 = __shfl_xor(v1, d); int oi1 = __shfl_xor(i1, d);
    merge2t(v0, i0, v1, i1, ov0, oi0, ov1, oi1);
  }
  if ((t & 63) == 0) wpair[t >> 6] = make_float4(v0, __int_as_float(i0),
                                                 v1, __int_as_float(i1));
  __syncthreads();
  if (t == 0) {
    float4 p = wpair[0];
    float m0v = p.x; int m0i = __float_as_int(p.y);
    float m1v = p.z; int m1i = __float_as_int(p.w);
    for (int wd = 1; wd < 4; ++wd) {
      float4 q = wpair[wd];
      merge2t(m0v, m0i, m1v, m1i, q.x, __float_as_int(q.y),
              q.z, __float_as_int(q.w));
    }
    sidx[0] = m0i; sidx[1] = m1i;
  }
  __syncthreads();
  const int idx0 = sidx[0], idx1 = sidx[1];

  // phase B: exact fp32 dot products / norms
  const float2* xin = (const float2*)(input  + (size_t)b * DIMS);
  const float2* xtg = (const float2*)(target + (size_t)b * DIMS);
  const float2* xv0 = (const float2*)(veclist + (size_t)idx0 * DIMS);
  const float2* xv1 = (const float2*)(veclist + (size_t)idx1 * DIMS);
  float2 xi = xin[t], tg = xtg[t], a0 = xv0[t], a1 = xv1[t];
  float s[7];
  s[0] = xi.x * xi.x + xi.y * xi.y;
  s[1] = tg.x * tg.x + tg.y * tg.y;
  s[2] = xi.x * tg.x + xi.y * tg.y;
  s[3] = a0.x * a0.x + a0.y * a0.y;
  s[4] = xi.x * a0.x + xi.y * a0.y;
  s[5] = a1.x * a1.x + a1.y * a1.y;
  s[6] = xi.x * a1.x + xi.y * a1.y;
  bool eq = (a0.x == tg.x) && (a0.y == tg.y);
  int weq = __all(eq);
  #pragma unroll
  for (int k = 0; k < 7; ++k)
    #pragma unroll
    for (int d = 1; d < 64; d <<= 1) s[k] += __shfl_xor(s[k], d);
  if ((t & 63) == 0) {
    #pragma unroll
    for (int k = 0; k < 7; ++k) red[t >> 6][k] = s[k];
    reda[t >> 6] = weq;
  }
  __syncthreads();
  if (t == 0) {
    float r[7];
    #pragma unroll
    for (int k = 0; k < 7; ++k)
      r[k] = red[0][k] + red[1][k] + red[2][k] + red[3][k];
    bool eq0 = reda[0] && reda[1] && reda[2] && reda[3];
    float na  = fmaxf(sqrtf(r[0]), EPSF);
    float ntg = fmaxf(sqrtf(r[1]), EPSF);
    float simp = r[2] / (na * ntg);
    float d_pos = sqrtf(fmaxf(2.0f * (1.0f - simp), 1e-12f));
    float nn = eq0 ? fmaxf(sqrtf(r[5]), EPSF) : fmaxf(sqrtf(r[3]), EPSF);
    float dn = eq0 ? r[6] : r[4];
    float simn = dn / (na * nn);
    float d_neg = sqrtf(fmaxf(2.0f * (1.0f - simn), 1e-12f));
    float margin = 0.5f + d_pos - d_neg;          // GAMMA + d_pos - d_neg
    float contrib = 2.0f * fmaxf(margin, 0.0f) * (1.0f / (float)B_ROWS);  // RANK=2
    atomicAdd(out, contrib);
  }
}

// ---------------------------------------------------------------------------
// Workspace layout (bytes):
//   vnn  fp8 [50048][512]     @ 0          : 25,624,576
//   inn  fp8 [4096][512]      @ 25,624,576 :  2,097,152
//   cands float4 [4096][392]  @ 27,721,728 : 25,690,112   (total ~53.4 MB)
// ---------------------------------------------------------------------------
extern "C" void kernel_launch(void* const* d_in, const int* in_sizes, int n_in,
                              void* d_out, int out_size, void* d_ws, size_t ws_size,
                              hipStream_t stream) {
  const float* input   = (const float*)d_in[0];
  const float* target  = (const float*)d_in[1];
  const float* veclist = (const float*)d_in[2];
  float* out = (float*)d_out;
  char* ws = (char*)d_ws;
  unsigned char* vnn = (unsigned char*)ws;
  unsigned char* inn = (unsigned char*)(ws + 25624576);
  float4* cands = (float4*)(ws + 27721728);

  normalize_rows_kernel<<<2048, 256, 0, stream>>>(veclist, vnn, V_ROWS, V_PAD, out);
  normalize_rows_kernel<<<512, 256, 0, stream>>>(input, inn, B_ROWS, B_ROWS, nullptr);
  gemm_top2_kernel<<<MTILES * NTILES, 256, 0, stream>>>(inn, vnn, cands);
  finalize_kernel<<<B_ROWS, 256, 0, stream>>>(input, target, veclist, cands, out);
}